// Round 19
// baseline (12368.770 us; speedup 1.0000x reference)
//
#include <hip/hip_runtime.h>

// CustomLSTM on MI355X. R19: R17/R18 structure (128 blocks x 32 gate-cols;
// Wh in LDS, Wx via fragment-major global copy, coherent sc0/sc1 h loads,
// no fences) with kwf FULLY sized: 16384 units = m(2) x g(256) x kh(2) x kk(16).

#define NBLK 128
#define TPB  512
#define T_   512
#define HS_OFF 33554432   // outputs floats
#define CS_OFF 33685504   // HS_OFF + 2*64*1024

typedef float  f32x4  __attribute__((ext_vector_type(4)));
typedef short  bf16x8 __attribute__((ext_vector_type(8)));

// ---- workspace byte offsets ----
#define WS_CTR  0u              // 69632: gctr[8][1024] | rctr[1024] | gflag[8][1024]
#define WS_W    69632u          // 4 * 8MB bf16 (permuted, [m][p][k])
#define WS_WXF  33624064u       // 16MB fragment-major Wx0|Wx1
#define WS_BIAS 50401280u       // 2*4096 f32
#define WS_XB   50434048u       // [T][B][D] bf16 = 64 MiB
#define WS_H0   117542912u      // ring: 2 x 65536 bf16, layout [oct128][row64][8]
#define WS_H1   117805056u
#define WS_MIN  118067200u

__device__ __forceinline__ unsigned short f2bf(float f) {
  union { float f; unsigned u; } v; v.f = f;
  return (unsigned short)((v.u + 0x7FFFu + ((v.u >> 16) & 1u)) >> 16);
}
__device__ __forceinline__ float fsig(float x) { return 1.0f / (1.0f + __expf(-x)); }
__device__ __forceinline__ float ftanh(float x) {
  x = fminf(15.0f, fmaxf(-15.0f, x));
  float e = __expf(2.0f * x);
  return (e - 1.0f) / (e + 1.0f);
}

// Permute+transpose+bf16 weights: wp[m][p][k] = bf16(W_m[k][orig(p)]).
__global__ void kw(const float* __restrict__ Wx0, const float* __restrict__ Wh0,
                   const float* __restrict__ Wx1, const float* __restrict__ Wh1,
                   unsigned short* __restrict__ wp) {
  __shared__ float tile[64][65];
  int tb = blockIdx.x;
  int m  = tb >> 10;
  int kt = (tb >> 6) & 15;
  int nt = tb & 63;
  const float* W = (m == 0) ? Wx0 : (m == 1) ? Wh0 : (m == 2) ? Wx1 : Wh1;
  unsigned short* O = wp + (size_t)m * 4194304u;
  int k0 = kt * 64, n0 = nt * 64;
  int tx = threadIdx.x & 63, tg = threadIdx.x >> 6;
  for (int r = tg; r < 64; r += 4)
    tile[r][tx] = W[(size_t)(k0 + r) * 4096 + n0 + tx];
  __syncthreads();
  for (int r = tg; r < 64; r += 4) {
    int n = n0 + r;
    int p = ((n & 1023) << 2) | (n >> 10);
    O[(size_t)p * 1024 + k0 + tx] = f2bf(tile[tx][r]);
  }
}

// Fragment-major copies of Wx0 (m0) and Wx1 (m2).
// 16384 units = m(2) x g(256) x kh(2) x kk(16); unit = 1KB, lane l holds
// fragment (col = g*16 + (l&15), k = kh*512 + kk*32 + (l>>4)*8 .. +7).
__global__ void kwf(const unsigned short* __restrict__ wp, unsigned short* __restrict__ wxf) {
  int unit = blockIdx.x * 4 + (threadIdx.x >> 6);   // 0..16383
  int lane = threadIdx.x & 63;
  int m  = unit >> 13;          // 0..1
  int r  = unit & 8191;
  int g  = r >> 5;              // 0..255
  int kh = (r >> 4) & 1;
  int kk = r & 15;
  const char* src = (const char*)wp + (size_t)m * 16777216u
                  + (size_t)(g * 16 + (lane & 15)) * 2048 + kh * 1024 + kk * 64 + (lane >> 4) * 16;
  char* dst = (char*)wxf + (size_t)m * 8388608 + (size_t)((g * 2 + kh) * 16 + kk) * 1024 + lane * 16;
  *(uint4*)dst = *(const uint4*)src;
}

// x [B][T][D] f32 -> xb [T*B][D] bf16 (row = t*64+b)
__global__ void kx(const float* __restrict__ x, unsigned short* __restrict__ xb) {
  int row = blockIdx.x;
  int t = row >> 6, b = row & 63;
  const float4* src = (const float4*)(x + ((size_t)b * 512 + t) * 1024);
  float4 f = src[threadIdx.x];
  ushort4 o; o.x = f2bf(f.x); o.y = f2bf(f.y); o.z = f2bf(f.z); o.w = f2bf(f.w);
  ((ushort4*)(xb + (size_t)row * 1024))[threadIdx.x] = o;
}

// bias permute + prime ring slot 1 with initial h states (bf16, [oct][row][8])
__global__ void kmisc(const float* __restrict__ b0, const float* __restrict__ b1,
                      const float* __restrict__ h0in,
                      float* __restrict__ biasP,
                      unsigned short* __restrict__ h0r, unsigned short* __restrict__ h1r) {
  int idx = blockIdx.x * 256 + threadIdx.x;
  if (idx < 8192) {
    int layer = idx >> 12, p = idx & 4095;
    int orig = (p & 3) * 1024 + (p >> 2);
    biasP[idx] = (layer ? b1 : b0)[orig];
  } else if (idx < 139264) {
    int e = idx - 8192;
    int layer = e >> 16, o = e & 65535;
    int row = o >> 10, col = o & 1023;
    unsigned short v = f2bf(h0in[layer * 65536 + o]);
    int dst = 65536 + (col >> 3) * 512 + row * 8 + (col & 7);
    if (layer) h1r[dst] = v; else h0r[dst] = v;
  }
}

// Persistent cooperative kernel. 128 blocks x 512 threads (8 waves).
// Block b: gate-cols 32b..32b+31 of BOTH layers (h oct b each ring).
// Wave w: rt=w&3 (rows), kh=w>>2 (K-half). kh0 finalizes L0, kh1 finalizes L1.
__global__ void __launch_bounds__(TPB, 2)
klstm(const float* __restrict__ c0_in,
      const unsigned short* __restrict__ wp,
      const unsigned short* __restrict__ wxf,
      const float* __restrict__ biasP,
      const unsigned short* __restrict__ xb,
      unsigned short* __restrict__ h0ring,
      unsigned short* __restrict__ h1ring,
      unsigned* __restrict__ ctrbase,
      float* __restrict__ out) {
  extern __shared__ char smem[];   // 64K Wh0 | 64K Wh1 | 16K red | 8K xred | 4K lh
  float* redF  = (float*)(smem + 131072);
  float* xredF = (float*)(smem + 147456);
  float* lhF   = (float*)(smem + 155648);
  unsigned* gctr  = ctrbase;               // [8][1024]
  unsigned* rctr  = ctrbase + 8192;        // [1024]
  unsigned* gflag = ctrbase + 9216;        // [8][1024]
  const int tid = threadIdx.x;
  const int w   = tid >> 6;
  const int l   = tid & 63;
  const int b   = blockIdx.x;
  const int n0  = b * 32;
  const int rt  = w & 3;
  const int kh  = w >> 2;                  // K-half AND finalize-layer
  const int rbase = rt * 16;
  const int khalf = kh * 512;
  const int grp   = b >> 4;                // 8 groups of 16 blocks

  // stage Wh0 (m=1) and Wh1 (m=3) 32-col slices, swizzled col-major
  for (int s = 0; s < 2; ++s) {
    const char* src = (const char*)wp + (size_t)(s ? 3u : 1u) * 8388608u + (size_t)n0 * 2048u;
    char* dst = smem + s * 65536;
    for (int i = tid; i < 4096; i += TPB) {
      int sb = i << 4;
      int c  = sb >> 11;               // col 0..31
      int kb = sb & 2047;
      *(uint4*)(dst + (c << 11) + (kb ^ ((c & 7) << 4))) = *(const uint4*)(src + sb);
    }
  }

  const float bias0 = biasP[kh * 4096 + n0 + (l & 15)];        // cg 0
  const float bias1 = biasP[kh * 4096 + n0 + 16 + (l & 15)];   // cg 1
  const int qb = l & ~3;
  const int jg0 = b * 8 + ((l & 15) >> 2);
  const int jg1 = jg0 + 4;

  float cr0[4], cr1[4];
  #pragma unroll
  for (int v = 0; v < 4; ++v) {
    int row = rbase + (l >> 4) * 4 + v;
    cr0[v] = c0_in[kh * 65536 + row * 1024 + jg0];
    cr1[v] = c0_in[kh * 65536 + row * 1024 + jg1];
  }

  const int ae0   = (rbase + (l & 15)) * 1024 + khalf + (l >> 4) * 8;  // xb
  const int hbase = ((khalf >> 3) + (l >> 4)) * 512 + (rbase + (l & 15)) * 8;
  const int kb2   = khalf * 2 + (l >> 4) * 16;
  const int swz   = (l & 7) << 4;
  const int cb0   = (l & 15) << 11;          // cg0 col byte base
  const int cb1   = (16 + (l & 15)) << 11;   // cg1
  // fragment-major global W bases (+ kk*1024 + l*16)
  const char* wx1f0 = (const char*)wxf + 8388608 + (size_t)(b * 4 + kh) * 16384;
  const char* wx1f1 = (const char*)wxf + 8388608 + (size_t)(b * 4 + 2 + kh) * 16384;
  const char* wx0f0 = (const char*)wxf + (size_t)(b * 4 + kh) * 16384;
  const char* wx0f1 = (const char*)wxf + (size_t)(b * 4 + 2 + kh) * 16384;

  __syncthreads();                         // weights visible

  // prologue: x[0]@Wx0 K-half, both cg
  f32x4 xacc0 = {0.f,0.f,0.f,0.f}, xacc1 = {0.f,0.f,0.f,0.f};
  {
    #pragma unroll
    for (int kk = 0; kk < 16; ++kk) {
      bf16x8 ax = *(const bf16x8*)(xb + ae0 + kk * 32);
      bf16x8 b0 = *(const bf16x8*)(wx0f0 + kk * 1024 + l * 16);
      bf16x8 b1 = *(const bf16x8*)(wx0f1 + kk * 1024 + l * 16);
      xacc0 = __builtin_amdgcn_mfma_f32_16x16x32_bf16(ax, b0, xacc0, 0, 0, 0);
      xacc1 = __builtin_amdgcn_mfma_f32_16x16x32_bf16(ax, b1, xacc1, 0, 0, 0);
    }
    if (kh) {   // publish K-half-1 x partial
      float* xr = xredF + (size_t)rt * 512 + (size_t)l * 8;
      #pragma unroll
      for (int v = 0; v < 4; ++v) { xr[v] = xacc0[v]; xr[4 + v] = xacc1[v]; }
    }
  }
  __syncthreads();

  for (int k = 0; k <= T_; ++k) {
    const unsigned short* h0p = h0ring + ((k + 1) & 1) * 65536;
    const unsigned short* h1p = h1ring + (k & 1) * 65536;

    // ---- coherent h burst (MALL-direct, no fence needed) ----
    bf16x8 hf0[16], hf1[16];
    #pragma unroll
    for (int kk = 0; kk < 16; ++kk) {
      const unsigned short* a0p = h0p + hbase + kk * 2048;
      const unsigned short* a1p = h1p + hbase + kk * 2048;
      asm volatile("global_load_dwordx4 %0, %1, off sc0 sc1" : "=v"(hf0[kk]) : "v"(a0p));
      asm volatile("global_load_dwordx4 %0, %1, off sc0 sc1" : "=v"(hf1[kk]) : "v"(a1p));
    }
    asm volatile("s_waitcnt vmcnt(0)" ::: "memory");
    __builtin_amdgcn_sched_barrier(0);

    // ---- GEMM: L0 (h0@Wh0) and L1 (h0@Wx1 + h1@Wh1), both cg ----
    f32x4 a00 = {0.f,0.f,0.f,0.f}, a01 = {0.f,0.f,0.f,0.f};
    f32x4 ax0 = {0.f,0.f,0.f,0.f}, ax1 = {0.f,0.f,0.f,0.f};
    f32x4 ah0 = {0.f,0.f,0.f,0.f}, ah1 = {0.f,0.f,0.f,0.f};
    #pragma unroll
    for (int kk = 0; kk < 16; ++kk) {
      const int ko = (kb2 + kk * 64) ^ swz;
      bf16x8 bh00 = *(const bf16x8*)(smem + cb0 + ko);
      bf16x8 bh01 = *(const bf16x8*)(smem + cb1 + ko);
      bf16x8 bh10 = *(const bf16x8*)(smem + 65536 + cb0 + ko);
      bf16x8 bh11 = *(const bf16x8*)(smem + 65536 + cb1 + ko);
      bf16x8 bx10 = *(const bf16x8*)(wx1f0 + kk * 1024 + l * 16);
      bf16x8 bx11 = *(const bf16x8*)(wx1f1 + kk * 1024 + l * 16);
      a00 = __builtin_amdgcn_mfma_f32_16x16x32_bf16(hf0[kk], bh00, a00, 0, 0, 0);
      a01 = __builtin_amdgcn_mfma_f32_16x16x32_bf16(hf0[kk], bh01, a01, 0, 0, 0);
      ax0 = __builtin_amdgcn_mfma_f32_16x16x32_bf16(hf0[kk], bx10, ax0, 0, 0, 0);
      ax1 = __builtin_amdgcn_mfma_f32_16x16x32_bf16(hf0[kk], bx11, ax1, 0, 0, 0);
      ah0 = __builtin_amdgcn_mfma_f32_16x16x32_bf16(hf1[kk], bh10, ah0, 0, 0, 0);
      ah1 = __builtin_amdgcn_mfma_f32_16x16x32_bf16(hf1[kk], bh11, ah1, 0, 0, 0);
    }

    { // publish the partial of the layer this wave does NOT finalize
      float* rb = redF + (size_t)w * 512 + (size_t)l * 8;
      if (kh == 0) {
        #pragma unroll
        for (int v = 0; v < 4; ++v) { rb[v] = ax0[v] + ah0[v]; rb[4 + v] = ax1[v] + ah1[v]; }
      } else {
        #pragma unroll
        for (int v = 0; v < 4; ++v) { rb[v] = a00[v]; rb[4 + v] = a01[v]; }
      }
    }
    __syncthreads();

    // ---- finalize own layer (own partial + partner's) ----
    f32x4 g0, g1;
    {
      const float* rb = redF + (size_t)(w ^ 4) * 512 + (size_t)l * 8;
      if (kh == 0) {
        const float* xr = xredF + (size_t)rt * 512 + (size_t)l * 8;
        #pragma unroll
        for (int v = 0; v < 4; ++v) {
          g0[v] = a00[v] + rb[v]     + xacc0[v] + xr[v];
          g1[v] = a01[v] + rb[4 + v] + xacc1[v] + xr[4 + v];
        }
      } else {
        #pragma unroll
        for (int v = 0; v < 4; ++v) {
          g0[v] = ax0[v] + ah0[v] + rb[v];
          g1[v] = ax1[v] + ah1[v] + rb[4 + v];
        }
      }
    }

    const bool active = kh ? (k >= 1) : (k < T_);
    f32x4 outA = {0.f,0.f,0.f,0.f}, outB = {0.f,0.f,0.f,0.f};
    if (active) {
      unsigned short* hw = kh ? (h1ring + ((k + 1) & 1) * 65536)
                              : (h0ring + (k & 1) * 65536);
      #pragma unroll
      for (int v = 0; v < 4; ++v) {
        float gv0 = g0[v] + bias0;
        float i0 = fsig(__shfl(gv0, qb)), f0 = fsig(__shfl(gv0, qb | 1));
        float n0_ = ftanh(__shfl(gv0, qb | 2)), o0 = fsig(__shfl(gv0, qb | 3));
        float c0v = f0 * cr0[v] + i0 * n0_;
        cr0[v] = c0v;
        float h0v = o0 * ftanh(c0v);
        float gv1 = g1[v] + bias1;
        float i1 = fsig(__shfl(gv1, qb)), f1 = fsig(__shfl(gv1, qb | 1));
        float n1_ = ftanh(__shfl(gv1, qb | 2)), o1 = fsig(__shfl(gv1, qb | 3));
        float c1v = f1 * cr1[v] + i1 * n1_;
        cr1[v] = c1v;
        float h1v = o1 * ftanh(c1v);
        if ((l & 3) == 0) {
          int row = (l >> 4) * 4 + v;
          lhF[w * 128 + row * 8 + ((l & 15) >> 2)]     = h0v;
          lhF[w * 128 + row * 8 + 4 + ((l & 15) >> 2)] = h1v;
        }
      }
      if (l < 16) {
        f32x4 hA = *(f32x4*)(lhF + w * 128 + l * 8);
        f32x4 hB = *(f32x4*)(lhF + w * 128 + l * 8 + 4);
        outA = hA; outB = hB;
        ushort4 uA, uB;
        uA.x = f2bf(hA[0]); uA.y = f2bf(hA[1]); uA.z = f2bf(hA[2]); uA.w = f2bf(hA[3]);
        uB.x = f2bf(hB[0]); uB.y = f2bf(hB[1]); uB.z = f2bf(hB[2]); uB.w = f2bf(hB[3]);
        union { ushort4 s; unsigned long long q; } pA, pB; pA.s = uA; pB.s = uB;
        unsigned long long* dst = (unsigned long long*)(hw + b * 512 + (rbase + l) * 8);
        __hip_atomic_store(dst,     pA.q, __ATOMIC_RELAXED, __HIP_MEMORY_SCOPE_AGENT);
        __hip_atomic_store(dst + 1, pB.q, __ATOMIC_RELAXED, __HIP_MEMORY_SCOPE_AGENT);
      }
    }

    // ---- barrier arrival (8x16 tree); no fences ----
    if (k < T_) {
      __syncthreads();                      // drain h stores block-wide
      if (tid == 0) {
        unsigned old = __hip_atomic_fetch_add(&gctr[grp * 1024 + k], 1u,
                                              __ATOMIC_RELAXED, __HIP_MEMORY_SCOPE_AGENT);
        if (old == 15u) {
          unsigned oldr = __hip_atomic_fetch_add(&rctr[k], 1u,
                                                 __ATOMIC_RELAXED, __HIP_MEMORY_SCOPE_AGENT);
          if (oldr == 7u) {
            #pragma unroll
            for (int gg = 0; gg < 8; ++gg)
              __hip_atomic_store(&gflag[gg * 1024 + k], 1u,
                                 __ATOMIC_RELAXED, __HIP_MEMORY_SCOPE_AGENT);
          }
        }
      }
    }

    // ---- overlap window: out stores + x[k+1]@Wx0 ----
    if (active && l < 16) {
      const int row = rbase + l;
      if (kh) {
        float* o = out + (size_t)row * 524288u + (size_t)(k - 1) * 1024u + b * 8;
        *(f32x4*)o = outA; *(f32x4*)(o + 4) = outB;
        if (k == T_) {
          float* h = out + HS_OFF + 65536 + row * 1024 + b * 8;
          *(f32x4*)h = outA; *(f32x4*)(h + 4) = outB;
        }
      } else if (k == T_ - 1) {
        float* h = out + HS_OFF + row * 1024 + b * 8;
        *(f32x4*)h = outA; *(f32x4*)(h + 4) = outB;
      }
    }
    if (k + 1 < T_) {
      const unsigned short* xt = xb + (size_t)(k + 1) * 65536u;
      f32x4 xa0 = {0.f,0.f,0.f,0.f}, xa1 = {0.f,0.f,0.f,0.f};
      #pragma unroll
      for (int kk = 0; kk < 16; ++kk) {
        bf16x8 ax = *(const bf16x8*)(xt + ae0 + kk * 32);
        bf16x8 b0 = *(const bf16x8*)(wx0f0 + kk * 1024 + l * 16);
        bf16x8 b1 = *(const bf16x8*)(wx0f1 + kk * 1024 + l * 16);
        xa0 = __builtin_amdgcn_mfma_f32_16x16x32_bf16(ax, b0, xa0, 0, 0, 0);
        xa1 = __builtin_amdgcn_mfma_f32_16x16x32_bf16(ax, b1, xa1, 0, 0, 0);
      }
      if (kh) {
        float* xr = xredF + (size_t)rt * 512 + (size_t)l * 8;
        #pragma unroll
        for (int v = 0; v < 4; ++v) { xr[v] = xa0[v]; xr[4 + v] = xa1[v]; }
      } else {
        xacc0 = xa0; xacc1 = xa1;
      }
    }

    // ---- barrier wait ----
    if (k < T_) {
      if (tid == 0) {
        unsigned spins = 0;
        while (__hip_atomic_load(&gflag[grp * 1024 + k], __ATOMIC_RELAXED, __HIP_MEMORY_SCOPE_AGENT) == 0u) {
          __builtin_amdgcn_s_sleep(1);
          if (++spins > 67108864u) break;   // safety: never wedge the GPU
        }
      }
      __syncthreads();
    }
  }

  // final cell states
  if ((l & 3) == 0) {
    #pragma unroll
    for (int v = 0; v < 4; ++v) {
      int row = rbase + (l >> 4) * 4 + v;
      out[CS_OFF + kh * 65536 + row * 1024 + jg0] = cr0[v];
      out[CS_OFF + kh * 65536 + row * 1024 + jg1] = cr1[v];
    }
  }
}

extern "C" void kernel_launch(void* const* d_in, const int* in_sizes, int n_in,
                              void* d_out, int out_size, void* d_ws, size_t ws_size,
                              hipStream_t stream) {
  const float* x   = (const float*)d_in[0];
  const float* h0  = (const float*)d_in[1];
  const float* c0  = (const float*)d_in[2];
  const float* Wx0 = (const float*)d_in[3];
  const float* Wh0 = (const float*)d_in[4];
  const float* b0  = (const float*)d_in[5];
  const float* Wx1 = (const float*)d_in[6];
  const float* Wh1 = (const float*)d_in[7];
  const float* b1  = (const float*)d_in[8];
  float* out = (float*)d_out;
  char* ws = (char*)d_ws;
  if (ws_size < (size_t)WS_MIN) return;   // workspace too small -> fail loudly

  unsigned* ctr       = (unsigned*)(ws + WS_CTR);
  unsigned short* wp  = (unsigned short*)(ws + WS_W);
  unsigned short* wxf = (unsigned short*)(ws + WS_WXF);
  float* biasP        = (float*)(ws + WS_BIAS);
  unsigned short* xbp = (unsigned short*)(ws + WS_XB);
  unsigned short* h0r = (unsigned short*)(ws + WS_H0);
  unsigned short* h1r = (unsigned short*)(ws + WS_H1);

  (void)hipMemsetAsync(ctr, 0, 69632, stream);
  hipLaunchKernelGGL(kw,    dim3(4096),  dim3(256), 0, stream, Wx0, Wh0, Wx1, Wh1, wp);
  hipLaunchKernelGGL(kwf,   dim3(4096),  dim3(256), 0, stream, wp, wxf);
  hipLaunchKernelGGL(kx,    dim3(32768), dim3(256), 0, stream, x, xbp);
  hipLaunchKernelGGL(kmisc, dim3(544),   dim3(256), 0, stream, b0, b1, h0, biasP, h0r, h1r);

  (void)hipFuncSetAttribute((const void*)klstm, hipFuncAttributeMaxDynamicSharedMemorySize, 159744);
  const float* c0a = c0; const unsigned short* wpa = wp; const unsigned short* wxa = wxf;
  const float* bpa = biasP; const unsigned short* xba = xbp;
  unsigned short* h0a = h0r; unsigned short* h1a = h1r;
  unsigned* ca = ctr; float* oa = out;
  void* args[] = {&c0a, &wpa, &wxa, &bpa, &xba, &h0a, &h1a, &ca, &oa};
  hipError_t e = hipLaunchCooperativeKernel((const void*)klstm, dim3(NBLK), dim3(TPB),
                                            args, 159744, stream);
  if (e != hipSuccess) {
    hipLaunchKernelGGL(klstm, dim3(NBLK), dim3(TPB), 159744, stream,
                       c0a, wpa, wxa, bpa, xba, h0a, h1a, ca, oa);
  }
}

// Round 20
// 5395.638 us; speedup vs baseline: 2.2924x; 2.2924x over previous
//
#include <hip/hip_runtime.h>

// CustomLSTM on MI355X: persistent cooperative kernel (R16 skeleton = best:
// fence-free, coherent sc0/sc1 h loads, all weights LDS-resident, 16x16 tree
// barrier, coalesced 8B h stores, x@Wx0 in overlap window).
// R20: split h burst — vmcnt(16) after hf0 so hf1's MALL RTT hides under the
// 32 hf0-dependent MFMAs; vmcnt(0) only before the 16 hf1 MFMAs.

#define NBLK 256
#define TPB  512
#define T_   512
#define HS_OFF 33554432   // outputs floats
#define CS_OFF 33685504   // HS_OFF + 2*64*1024

typedef float  f32x4  __attribute__((ext_vector_type(4)));
typedef short  bf16x8 __attribute__((ext_vector_type(8)));

// ---- workspace byte offsets ----
#define WS_CTR  0u              // 139264: gctr[16][1024] | rctr[1024] | gflag[16][1024]
#define WS_W    139264u         // 4 * (4096*1024) bf16 = 32 MiB (permuted, [m][p][k])
#define WS_BIAS 33693696u       // 2*4096 f32
#define WS_XB   33726464u       // [T][B][D] bf16 = 64 MiB
#define WS_H0   100835328u      // ring: 2 * 65536 bf16, layout [oct][row][8]
#define WS_H1   101097472u
#define WS_MIN  101359616u

__device__ __forceinline__ unsigned short f2bf(float f) {
  union { float f; unsigned u; } v; v.f = f;
  return (unsigned short)((v.u + 0x7FFFu + ((v.u >> 16) & 1u)) >> 16);
}
__device__ __forceinline__ float fsig(float x) { return 1.0f / (1.0f + __expf(-x)); }
__device__ __forceinline__ float ftanh(float x) {
  x = fminf(15.0f, fmaxf(-15.0f, x));
  float e = __expf(2.0f * x);
  return (e - 1.0f) / (e + 1.0f);
}

// Permute+transpose+bf16 the 4 weight matrices: out[m][p][k] = bf16(W_m[k][orig(p)]),
// orig(p) = (p&3)*1024 + (p>>2)  (p = 4*j + gate). 64x64 tiles via LDS.
__global__ void kw(const float* __restrict__ Wx0, const float* __restrict__ Wh0,
                   const float* __restrict__ Wx1, const float* __restrict__ Wh1,
                   unsigned short* __restrict__ wp) {
  __shared__ float tile[64][65];
  int tb = blockIdx.x;
  int m  = tb >> 10;
  int kt = (tb >> 6) & 15;
  int nt = tb & 63;
  const float* W = (m == 0) ? Wx0 : (m == 1) ? Wh0 : (m == 2) ? Wx1 : Wh1;
  unsigned short* O = wp + (size_t)m * 4194304u;
  int k0 = kt * 64, n0 = nt * 64;
  int tx = threadIdx.x & 63, tg = threadIdx.x >> 6;
  for (int r = tg; r < 64; r += 4)
    tile[r][tx] = W[(size_t)(k0 + r) * 4096 + n0 + tx];
  __syncthreads();
  for (int r = tg; r < 64; r += 4) {
    int n = n0 + r;
    int p = ((n & 1023) << 2) | (n >> 10);
    O[(size_t)p * 1024 + k0 + tx] = f2bf(tile[tx][r]);
  }
}

// x [B][T][D] f32 -> xb [T*B][D] bf16 (row = t*64+b)
__global__ void kx(const float* __restrict__ x, unsigned short* __restrict__ xb) {
  int row = blockIdx.x;
  int t = row >> 6, b = row & 63;
  const float4* src = (const float4*)(x + ((size_t)b * 512 + t) * 1024);
  float4 f = src[threadIdx.x];
  ushort4 o; o.x = f2bf(f.x); o.y = f2bf(f.y); o.z = f2bf(f.z); o.w = f2bf(f.w);
  ((ushort4*)(xb + (size_t)row * 1024))[threadIdx.x] = o;
}

// bias permute + prime ring slot 1 with initial h states (bf16, [oct][row][8])
__global__ void kmisc(const float* __restrict__ b0, const float* __restrict__ b1,
                      const float* __restrict__ h0in,
                      float* __restrict__ biasP,
                      unsigned short* __restrict__ h0r, unsigned short* __restrict__ h1r) {
  int idx = blockIdx.x * 256 + threadIdx.x;
  if (idx < 8192) {
    int layer = idx >> 12, p = idx & 4095;
    int orig = (p & 3) * 1024 + (p >> 2);
    biasP[idx] = (layer ? b1 : b0)[orig];
  } else if (idx < 139264) {
    int e = idx - 8192;
    int layer = e >> 16, o = e & 65535;
    int row = o >> 10, col = o & 1023;
    unsigned short v = f2bf(h0in[layer * 65536 + o]);
    int dst = 65536 + (col >> 3) * 512 + row * 8 + (col & 7);
    if (layer) h1r[dst] = v; else h0r[dst] = v;
  }
}

// Persistent cooperative kernel. 256 blocks x 512 threads (8 waves).
// Wave w: rows 16*(w&3), K-half (w>>2)*512, finalizes layer (w>>2).
// All 4 weight slices in LDS; h fragments loaded COHERENT (sc0 sc1) with a
// SPLIT waitcnt (vmcnt(16) / vmcnt(0)) so hf1 latency hides under hf0 MFMAs.
__global__ void __launch_bounds__(TPB, 2)
klstm(const float* __restrict__ c0_in,
      const unsigned short* __restrict__ wp,
      const float* __restrict__ biasP,
      const unsigned short* __restrict__ xb,
      unsigned short* __restrict__ h0ring,
      unsigned short* __restrict__ h1ring,
      unsigned* __restrict__ ctrbase,
      float* __restrict__ out) {
  extern __shared__ char smem[];   // 32K Wx0 | 32K Wx1 | 32K Wh0 | 32K Wh1 | 8K red | 2K lh | 4K xred
  float* red  = (float*)(smem + 131072);
  float* lhb  = (float*)(smem + 139264);
  float* xred = (float*)(smem + 141312);
  unsigned* gctr  = ctrbase;               // [16][1024]
  unsigned* rctr  = ctrbase + 16384;       // [1024]
  unsigned* gflag = ctrbase + 17408;       // [16][1024]
  const int tid = threadIdx.x;
  const int w   = tid >> 6;
  const int l   = tid & 63;
  const int bid = blockIdx.x;
  const int n0  = bid * 16;
  const int layer = w >> 2;
  const int rbase = (w & 3) * 16;
  const int khalf = (w >> 2) * 512;
  const int grp   = bid >> 4;              // 16 groups of 16 blocks
  float* lh = lhb + w * 64;                // [16 rows][4 cols] f32 per wave

  // stage all 4 weight slices into LDS: slot0=Wx0(m0) slot1=Wx1(m2) slot2=Wh0(m1) slot3=Wh1(m3)
  {
    const int msrc[4] = {0, 2, 1, 3};
    for (int s = 0; s < 4; ++s) {
      const char* src = (const char*)(wp + (size_t)msrc[s] * 4194304u + (size_t)n0 * 1024u);
      char* dst = smem + s * 32768;
      for (int i = tid; i < 2048; i += TPB) {
        int sb = i << 4;
        int c  = sb >> 11;
        int kb = sb & 2047;
        *(uint4*)(dst + (c << 11) + (kb ^ ((c & 7) << 4))) = *(const uint4*)(src + sb);
      }
    }
  }

  const int jg = bid * 4 + ((l & 15) >> 2);   // global h column (gate finalize)
  const float biasv = biasP[layer * 4096 + n0 + (l & 15)];
  const int qb = l & ~3;

  float cr[4];
  #pragma unroll
  for (int v = 0; v < 4; ++v)
    cr[v] = c0_in[layer * 65536 + (rbase + (l >> 4) * 4 + v) * 1024 + jg];

  const int ae0  = (rbase + (l & 15)) * 1024 + khalf + (l >> 4) * 8;  // xb (row-major)
  const int hbase = ((khalf >> 3) + (l >> 4)) * 512 + (rbase + (l & 15)) * 8;
  const int lb0  = (l & 15) << 11;
  const int kb2  = khalf * 2 + (l >> 4) * 16;
  const int swz  = (l & 7) << 4;
  const int hsto = (bid >> 1) * 512 + 4 * (bid & 1);

  __syncthreads();                         // weight staging visible

  // prologue: x[0]@Wx0 slice for this wave
  f32x4 xacc = {0.f, 0.f, 0.f, 0.f};
  {
    #pragma unroll
    for (int kk = 0; kk < 16; ++kk) {
      bf16x8 ax = *(const bf16x8*)(xb + ae0 + kk * 32);
      bf16x8 b  = *(const bf16x8*)(smem + lb0 + ((kb2 + kk * 64) ^ swz));
      xacc = __builtin_amdgcn_mfma_f32_16x16x32_bf16(ax, b, xacc, 0, 0, 0);
    }
    if (w >= 4) {
      float* xr = xred + (size_t)(w & 3) * 256 + (size_t)l * 4;
      #pragma unroll
      for (int v = 0; v < 4; ++v) xr[v] = xacc[v];
    }
  }
  __syncthreads();

  for (int k = 0; k <= T_; ++k) {
    const unsigned short* h0p = h0ring + ((k + 1) & 1) * 65536;
    const unsigned short* h1p = h1ring + (k & 1) * 65536;

    // ---- coherent h burst, SPLIT: hf0 first, then hf1 ----
    bf16x8 hf0[16], hf1[16];
    __builtin_amdgcn_sched_barrier(0);
    #pragma unroll
    for (int kk = 0; kk < 16; ++kk) {
      const unsigned short* a0p = h0p + hbase + kk * 2048;
      asm volatile("global_load_dwordx4 %0, %1, off sc0 sc1" : "=v"(hf0[kk]) : "v"(a0p));
    }
    #pragma unroll
    for (int kk = 0; kk < 16; ++kk) {
      const unsigned short* a1p = h1p + hbase + kk * 2048;
      asm volatile("global_load_dwordx4 %0, %1, off sc0 sc1" : "=v"(hf1[kk]) : "v"(a1p));
    }
    asm volatile("s_waitcnt vmcnt(16)" ::: "memory");   // hf0 complete (FIFO: older ops drain first)
    __builtin_amdgcn_sched_barrier(0);

    f32x4 acc0  = {0.f, 0.f, 0.f, 0.f};
    f32x4 acc1a = {0.f, 0.f, 0.f, 0.f};
    f32x4 acc1b = {0.f, 0.f, 0.f, 0.f};
    #pragma unroll
    for (int kk = 0; kk < 16; ++kk) {
      const int bo = lb0 + ((kb2 + kk * 64) ^ swz);
      bf16x8 bh0 = *(const bf16x8*)(smem + 65536 + bo);
      bf16x8 bx1 = *(const bf16x8*)(smem + 32768 + bo);
      acc0  = __builtin_amdgcn_mfma_f32_16x16x32_bf16(hf0[kk], bh0, acc0, 0, 0, 0);
      acc1a = __builtin_amdgcn_mfma_f32_16x16x32_bf16(hf0[kk], bx1, acc1a, 0, 0, 0);
    }
    asm volatile("s_waitcnt vmcnt(0)" ::: "memory");    // hf1 complete
    __builtin_amdgcn_sched_barrier(0);
    #pragma unroll
    for (int kk = 0; kk < 16; ++kk) {
      const int bo = lb0 + ((kb2 + kk * 64) ^ swz);
      bf16x8 bh1 = *(const bf16x8*)(smem + 98304 + bo);
      acc1b = __builtin_amdgcn_mfma_f32_16x16x32_bf16(hf1[kk], bh1, acc1b, 0, 0, 0);
    }

    { // publish the other layer's partial for the partner wave
      float* rb = red + (size_t)(w * 64 + l) * 4;
      f32x4 other = layer ? acc0 : (acc1a + acc1b);
      #pragma unroll
      for (int v = 0; v < 4; ++v) rb[v] = other[v];
    }
    __syncthreads();

    f32x4 g = layer ? (acc1a + acc1b) : acc0;
    {
      const int pw = layer ? (w - 4) : (w + 4);
      const float* rb = red + (size_t)(pw * 64 + l) * 4;
      #pragma unroll
      for (int v = 0; v < 4; ++v) g[v] += rb[v];
    }
    if (w < 4) {   // + x@Wx0: own half (regs) + partner half (xred)
      const float* xr = xred + (size_t)w * 256 + (size_t)l * 4;
      #pragma unroll
      for (int v = 0; v < 4; ++v) g[v] += xacc[v] + xr[v];
    }

    const bool active = layer ? (k >= 1) : (k < T_);
    f32x4 outv = {0.f, 0.f, 0.f, 0.f};
    if (active) {
      unsigned short* hw = layer ? (h1ring + ((k + 1) & 1) * 65536)
                                 : (h0ring + (k & 1) * 65536);
      #pragma unroll
      for (int v = 0; v < 4; ++v) {
        float gv = g[v] + biasv;
        float gi = __shfl(gv, qb);
        float gf = __shfl(gv, qb | 1);
        float gn = __shfl(gv, qb | 2);
        float go = __shfl(gv, qb | 3);
        float i_ = fsig(gi), f_ = fsig(gf), n_ = ftanh(gn), o_ = fsig(go);
        float c = f_ * cr[v] + i_ * n_;
        cr[v] = c;
        float h = o_ * ftanh(c);
        if ((l & 3) == 0)
          lh[((l >> 4) * 4 + v) * 4 + ((l & 15) >> 2)] = h;   // repack tile
      }
      if (l < 16) {   // same-wave read-back: coalesced 8B agent store
        f32x4 h4 = *(f32x4*)(lh + l * 4);
        outv = h4;
        ushort4 u4;
        u4.x = f2bf(h4[0]); u4.y = f2bf(h4[1]); u4.z = f2bf(h4[2]); u4.w = f2bf(h4[3]);
        union { ushort4 s; unsigned long long q; } pk; pk.s = u4;
        __hip_atomic_store((unsigned long long*)(hw + hsto + (rbase + l) * 8), pk.q,
                           __ATOMIC_RELAXED, __HIP_MEMORY_SCOPE_AGENT);
      }
    }

    // ---- barrier arrival (16x16 tree); NO fence anywhere ----
    if (k < T_) {
      __syncthreads();                      // drain h stores block-wide
      if (tid == 0) {
        unsigned old = __hip_atomic_fetch_add(&gctr[grp * 1024 + k], 1u,
                                              __ATOMIC_RELAXED, __HIP_MEMORY_SCOPE_AGENT);
        if (old == 15u) {
          unsigned oldr = __hip_atomic_fetch_add(&rctr[k], 1u,
                                                 __ATOMIC_RELAXED, __HIP_MEMORY_SCOPE_AGENT);
          if (oldr == 15u) {
            #pragma unroll
            for (int gg = 0; gg < 16; ++gg)
              __hip_atomic_store(&gflag[gg * 1024 + k], 1u,
                                 __ATOMIC_RELAXED, __HIP_MEMORY_SCOPE_AGENT);
          }
        }
      }
    }

    // ---- overlap window: out stores + x[k+1]@Wx0 slice (dead-time work) ----
    if (active && l < 16) {
      const int row = rbase + l;
      if (layer) {
        *(f32x4*)(out + (size_t)row * 524288u + (size_t)(k - 1) * 1024u + bid * 4) = outv;
        if (k == T_)
          *(f32x4*)(out + HS_OFF + 65536 + row * 1024 + bid * 4) = outv;
      } else if (k == T_ - 1) {
        *(f32x4*)(out + HS_OFF + row * 1024 + bid * 4) = outv;
      }
    }
    if (k + 1 < T_) {
      const unsigned short* xt = xb + (size_t)(k + 1) * 65536u;
      f32x4 xa = {0.f, 0.f, 0.f, 0.f};
      #pragma unroll
      for (int kk = 0; kk < 16; ++kk) {
        bf16x8 ax = *(const bf16x8*)(xt + ae0 + kk * 32);
        bf16x8 b  = *(const bf16x8*)(smem + lb0 + ((kb2 + kk * 64) ^ swz));
        xa = __builtin_amdgcn_mfma_f32_16x16x32_bf16(ax, b, xa, 0, 0, 0);
      }
      if (w >= 4) {   // publish K-half-1 partial; consumed at step k+1 finalize
        float* xr = xred + (size_t)(w & 3) * 256 + (size_t)l * 4;
        #pragma unroll
        for (int v = 0; v < 4; ++v) xr[v] = xa[v];
      } else {
        xacc = xa;
      }
    }

    // ---- barrier wait (per-group flag line); syncthreads = ordering fence ----
    if (k < T_) {
      if (tid == 0) {
        unsigned spins = 0;
        while (__hip_atomic_load(&gflag[grp * 1024 + k], __ATOMIC_RELAXED, __HIP_MEMORY_SCOPE_AGENT) == 0u) {
          __builtin_amdgcn_s_sleep(1);
          if (++spins > 67108864u) break;   // safety: never wedge the GPU
        }
      }
      __syncthreads();
    }
  }

  // final cell states (rare, scattered is fine)
  if ((l & 3) == 0) {
    #pragma unroll
    for (int v = 0; v < 4; ++v)
      out[CS_OFF + layer * 65536 + (rbase + (l >> 4) * 4 + v) * 1024 + jg] = cr[v];
  }
}

extern "C" void kernel_launch(void* const* d_in, const int* in_sizes, int n_in,
                              void* d_out, int out_size, void* d_ws, size_t ws_size,
                              hipStream_t stream) {
  const float* x   = (const float*)d_in[0];
  const float* h0  = (const float*)d_in[1];
  const float* c0  = (const float*)d_in[2];
  const float* Wx0 = (const float*)d_in[3];
  const float* Wh0 = (const float*)d_in[4];
  const float* b0  = (const float*)d_in[5];
  const float* Wx1 = (const float*)d_in[6];
  const float* Wh1 = (const float*)d_in[7];
  const float* b1  = (const float*)d_in[8];
  float* out = (float*)d_out;
  char* ws = (char*)d_ws;
  if (ws_size < (size_t)WS_MIN) return;   // workspace too small -> fail loudly

  unsigned* ctr       = (unsigned*)(ws + WS_CTR);
  unsigned short* wp  = (unsigned short*)(ws + WS_W);
  float* biasP        = (float*)(ws + WS_BIAS);
  unsigned short* xbp = (unsigned short*)(ws + WS_XB);
  unsigned short* h0r = (unsigned short*)(ws + WS_H0);
  unsigned short* h1r = (unsigned short*)(ws + WS_H1);

  (void)hipMemsetAsync(ctr, 0, 139264, stream);
  hipLaunchKernelGGL(kw,    dim3(4096),  dim3(256), 0, stream, Wx0, Wh0, Wx1, Wh1, wp);
  hipLaunchKernelGGL(kx,    dim3(32768), dim3(256), 0, stream, x, xbp);
  hipLaunchKernelGGL(kmisc, dim3(544),   dim3(256), 0, stream, b0, b1, h0, biasP, h0r, h1r);

  (void)hipFuncSetAttribute((const void*)klstm, hipFuncAttributeMaxDynamicSharedMemorySize, 145408);
  const float* c0a = c0; const unsigned short* wpa = wp; const float* bpa = biasP;
  const unsigned short* xba = xbp;
  unsigned short* h0a = h0r; unsigned short* h1a = h1r;
  unsigned* ca = ctr; float* oa = out;
  void* args[] = {&c0a, &wpa, &bpa, &xba, &h0a, &h1a, &ca, &oa};
  hipError_t e = hipLaunchCooperativeKernel((const void*)klstm, dim3(NBLK), dim3(TPB),
                                            args, 145408, stream);
  if (e != hipSuccess) {
    hipLaunchKernelGGL(klstm, dim3(NBLK), dim3(TPB), 145408, stream,
                       c0a, wpa, bpa, xba, h0a, h1a, ca, oa);
  }
}

// Round 21
// 4792.797 us; speedup vs baseline: 2.5807x; 1.1258x over previous
//
#include <hip/hip_runtime.h>

// CustomLSTM on MI355X: persistent cooperative kernel (R16 configuration —
// best measured). Fence-free: h fragments loaded with `global_load_dwordx4
// sc0 sc1` (coherent at MALL); all weights LDS-resident; 16x16 tree barrier;
// coalesced 8B h stores; x@Wx0 computed in the barrier-wait overlap window.

#define NBLK 256
#define TPB  512
#define T_   512
#define HS_OFF 33554432   // outputs floats
#define CS_OFF 33685504   // HS_OFF + 2*64*1024

typedef float  f32x4  __attribute__((ext_vector_type(4)));
typedef short  bf16x8 __attribute__((ext_vector_type(8)));

// ---- workspace byte offsets ----
#define WS_CTR  0u              // 139264: gctr[16][1024] | rctr[1024] | gflag[16][1024]
#define WS_W    139264u         // 4 * (4096*1024) bf16 = 32 MiB (permuted, [m][p][k])
#define WS_BIAS 33693696u       // 2*4096 f32
#define WS_XB   33726464u       // [T][B][D] bf16 = 64 MiB
#define WS_H0   100835328u      // ring: 2 * 65536 bf16, layout [oct][row][8]
#define WS_H1   101097472u
#define WS_MIN  101359616u

__device__ __forceinline__ unsigned short f2bf(float f) {
  union { float f; unsigned u; } v; v.f = f;
  return (unsigned short)((v.u + 0x7FFFu + ((v.u >> 16) & 1u)) >> 16);
}
__device__ __forceinline__ float fsig(float x) { return 1.0f / (1.0f + __expf(-x)); }
__device__ __forceinline__ float ftanh(float x) {
  x = fminf(15.0f, fmaxf(-15.0f, x));
  float e = __expf(2.0f * x);
  return (e - 1.0f) / (e + 1.0f);
}

// Permute+transpose+bf16 the 4 weight matrices: out[m][p][k] = bf16(W_m[k][orig(p)]),
// orig(p) = (p&3)*1024 + (p>>2)  (p = 4*j + gate). 64x64 tiles via LDS.
__global__ void kw(const float* __restrict__ Wx0, const float* __restrict__ Wh0,
                   const float* __restrict__ Wx1, const float* __restrict__ Wh1,
                   unsigned short* __restrict__ wp) {
  __shared__ float tile[64][65];
  int tb = blockIdx.x;
  int m  = tb >> 10;
  int kt = (tb >> 6) & 15;
  int nt = tb & 63;
  const float* W = (m == 0) ? Wx0 : (m == 1) ? Wh0 : (m == 2) ? Wx1 : Wh1;
  unsigned short* O = wp + (size_t)m * 4194304u;
  int k0 = kt * 64, n0 = nt * 64;
  int tx = threadIdx.x & 63, tg = threadIdx.x >> 6;
  for (int r = tg; r < 64; r += 4)
    tile[r][tx] = W[(size_t)(k0 + r) * 4096 + n0 + tx];
  __syncthreads();
  for (int r = tg; r < 64; r += 4) {
    int n = n0 + r;
    int p = ((n & 1023) << 2) | (n >> 10);
    O[(size_t)p * 1024 + k0 + tx] = f2bf(tile[tx][r]);
  }
}

// x [B][T][D] f32 -> xb [T*B][D] bf16 (row = t*64+b)
__global__ void kx(const float* __restrict__ x, unsigned short* __restrict__ xb) {
  int row = blockIdx.x;
  int t = row >> 6, b = row & 63;
  const float4* src = (const float4*)(x + ((size_t)b * 512 + t) * 1024);
  float4 f = src[threadIdx.x];
  ushort4 o; o.x = f2bf(f.x); o.y = f2bf(f.y); o.z = f2bf(f.z); o.w = f2bf(f.w);
  ((ushort4*)(xb + (size_t)row * 1024))[threadIdx.x] = o;
}

// bias permute + prime ring slot 1 with initial h states (bf16, [oct][row][8])
__global__ void kmisc(const float* __restrict__ b0, const float* __restrict__ b1,
                      const float* __restrict__ h0in,
                      float* __restrict__ biasP,
                      unsigned short* __restrict__ h0r, unsigned short* __restrict__ h1r) {
  int idx = blockIdx.x * 256 + threadIdx.x;
  if (idx < 8192) {
    int layer = idx >> 12, p = idx & 4095;
    int orig = (p & 3) * 1024 + (p >> 2);
    biasP[idx] = (layer ? b1 : b0)[orig];
  } else if (idx < 139264) {
    int e = idx - 8192;
    int layer = e >> 16, o = e & 65535;
    int row = o >> 10, col = o & 1023;
    unsigned short v = f2bf(h0in[layer * 65536 + o]);
    int dst = 65536 + (col >> 3) * 512 + row * 8 + (col & 7);
    if (layer) h1r[dst] = v; else h0r[dst] = v;
  }
}

// Persistent cooperative kernel. 256 blocks x 512 threads (8 waves).
// Wave w: rows 16*(w&3), K-half (w>>2)*512, finalizes layer (w>>2).
// All 4 weight slices in LDS; h fragments loaded COHERENT (sc0 sc1) in one
// asm burst — no per-step fence/inv anywhere.
__global__ void __launch_bounds__(TPB, 2)
klstm(const float* __restrict__ c0_in,
      const unsigned short* __restrict__ wp,
      const float* __restrict__ biasP,
      const unsigned short* __restrict__ xb,
      unsigned short* __restrict__ h0ring,
      unsigned short* __restrict__ h1ring,
      unsigned* __restrict__ ctrbase,
      float* __restrict__ out) {
  extern __shared__ char smem[];   // 32K Wx0 | 32K Wx1 | 32K Wh0 | 32K Wh1 | 8K red | 2K lh | 4K xred
  float* red  = (float*)(smem + 131072);
  float* lhb  = (float*)(smem + 139264);
  float* xred = (float*)(smem + 141312);
  unsigned* gctr  = ctrbase;               // [16][1024]
  unsigned* rctr  = ctrbase + 16384;       // [1024]
  unsigned* gflag = ctrbase + 17408;       // [16][1024]
  const int tid = threadIdx.x;
  const int w   = tid >> 6;
  const int l   = tid & 63;
  const int bid = blockIdx.x;
  const int n0  = bid * 16;
  const int layer = w >> 2;
  const int rbase = (w & 3) * 16;
  const int khalf = (w >> 2) * 512;
  const int grp   = bid >> 4;              // 16 groups of 16 blocks
  float* lh = lhb + w * 64;                // [16 rows][4 cols] f32 per wave

  // stage all 4 weight slices into LDS: slot0=Wx0(m0) slot1=Wx1(m2) slot2=Wh0(m1) slot3=Wh1(m3)
  {
    const int msrc[4] = {0, 2, 1, 3};
    for (int s = 0; s < 4; ++s) {
      const char* src = (const char*)(wp + (size_t)msrc[s] * 4194304u + (size_t)n0 * 1024u);
      char* dst = smem + s * 32768;
      for (int i = tid; i < 2048; i += TPB) {
        int sb = i << 4;
        int c  = sb >> 11;
        int kb = sb & 2047;
        *(uint4*)(dst + (c << 11) + (kb ^ ((c & 7) << 4))) = *(const uint4*)(src + sb);
      }
    }
  }

  const int jg = bid * 4 + ((l & 15) >> 2);   // global h column (gate finalize)
  const float biasv = biasP[layer * 4096 + n0 + (l & 15)];
  const int qb = l & ~3;

  float cr[4];
  #pragma unroll
  for (int v = 0; v < 4; ++v)
    cr[v] = c0_in[layer * 65536 + (rbase + (l >> 4) * 4 + v) * 1024 + jg];

  const int ae0  = (rbase + (l & 15)) * 1024 + khalf + (l >> 4) * 8;  // xb (row-major)
  const int hbase = ((khalf >> 3) + (l >> 4)) * 512 + (rbase + (l & 15)) * 8;
  const int lb0  = (l & 15) << 11;
  const int kb2  = khalf * 2 + (l >> 4) * 16;
  const int swz  = (l & 7) << 4;
  const int hsto = (bid >> 1) * 512 + 4 * (bid & 1);

  __syncthreads();                         // weight staging visible

  // prologue: x[0]@Wx0 slice for this wave
  f32x4 xacc = {0.f, 0.f, 0.f, 0.f};
  {
    #pragma unroll
    for (int kk = 0; kk < 16; ++kk) {
      bf16x8 ax = *(const bf16x8*)(xb + ae0 + kk * 32);
      bf16x8 b  = *(const bf16x8*)(smem + lb0 + ((kb2 + kk * 64) ^ swz));
      xacc = __builtin_amdgcn_mfma_f32_16x16x32_bf16(ax, b, xacc, 0, 0, 0);
    }
    if (w >= 4) {
      float* xr = xred + (size_t)(w & 3) * 256 + (size_t)l * 4;
      #pragma unroll
      for (int v = 0; v < 4; ++v) xr[v] = xacc[v];
    }
  }
  __syncthreads();

  for (int k = 0; k <= T_; ++k) {
    const unsigned short* h0p = h0ring + ((k + 1) & 1) * 65536;
    const unsigned short* h1p = h1ring + (k & 1) * 65536;

    // ---- coherent h burst: 32 x global_load_dwordx4 sc0 sc1 (MALL-direct) ----
    bf16x8 hf0[16], hf1[16];
    #pragma unroll
    for (int kk = 0; kk < 16; ++kk) {
      const unsigned short* a0p = h0p + hbase + kk * 2048;
      const unsigned short* a1p = h1p + hbase + kk * 2048;
      asm volatile("global_load_dwordx4 %0, %1, off sc0 sc1"
                   : "=v"(hf0[kk]) : "v"(a0p));
      asm volatile("global_load_dwordx4 %0, %1, off sc0 sc1"
                   : "=v"(hf1[kk]) : "v"(a1p));
    }
    asm volatile("s_waitcnt vmcnt(0)" ::: "memory");
    __builtin_amdgcn_sched_barrier(0);

    f32x4 acc0  = {0.f, 0.f, 0.f, 0.f};
    f32x4 acc1a = {0.f, 0.f, 0.f, 0.f};
    f32x4 acc1b = {0.f, 0.f, 0.f, 0.f};
    #pragma unroll
    for (int kk = 0; kk < 16; ++kk) {
      const int bo = lb0 + ((kb2 + kk * 64) ^ swz);
      bf16x8 bh0 = *(const bf16x8*)(smem + 65536 + bo);
      bf16x8 bx1 = *(const bf16x8*)(smem + 32768 + bo);
      bf16x8 bh1 = *(const bf16x8*)(smem + 98304 + bo);
      acc0  = __builtin_amdgcn_mfma_f32_16x16x32_bf16(hf0[kk], bh0, acc0, 0, 0, 0);
      acc1a = __builtin_amdgcn_mfma_f32_16x16x32_bf16(hf0[kk], bx1, acc1a, 0, 0, 0);
      acc1b = __builtin_amdgcn_mfma_f32_16x16x32_bf16(hf1[kk], bh1, acc1b, 0, 0, 0);
    }

    { // publish the other layer's partial for the partner wave
      float* rb = red + (size_t)(w * 64 + l) * 4;
      f32x4 other = layer ? acc0 : (acc1a + acc1b);
      #pragma unroll
      for (int v = 0; v < 4; ++v) rb[v] = other[v];
    }
    __syncthreads();

    f32x4 g = layer ? (acc1a + acc1b) : acc0;
    {
      const int pw = layer ? (w - 4) : (w + 4);
      const float* rb = red + (size_t)(pw * 64 + l) * 4;
      #pragma unroll
      for (int v = 0; v < 4; ++v) g[v] += rb[v];
    }
    if (w < 4) {   // + x@Wx0: own half (regs) + partner half (xred)
      const float* xr = xred + (size_t)w * 256 + (size_t)l * 4;
      #pragma unroll
      for (int v = 0; v < 4; ++v) g[v] += xacc[v] + xr[v];
    }

    const bool active = layer ? (k >= 1) : (k < T_);
    f32x4 outv = {0.f, 0.f, 0.f, 0.f};
    if (active) {
      unsigned short* hw = layer ? (h1ring + ((k + 1) & 1) * 65536)
                                 : (h0ring + (k & 1) * 65536);
      #pragma unroll
      for (int v = 0; v < 4; ++v) {
        float gv = g[v] + biasv;
        float gi = __shfl(gv, qb);
        float gf = __shfl(gv, qb | 1);
        float gn = __shfl(gv, qb | 2);
        float go = __shfl(gv, qb | 3);
        float i_ = fsig(gi), f_ = fsig(gf), n_ = ftanh(gn), o_ = fsig(go);
        float c = f_ * cr[v] + i_ * n_;
        cr[v] = c;
        float h = o_ * ftanh(c);
        if ((l & 3) == 0)
          lh[((l >> 4) * 4 + v) * 4 + ((l & 15) >> 2)] = h;   // repack tile
      }
      if (l < 16) {   // same-wave read-back: coalesced 8B agent store
        f32x4 h4 = *(f32x4*)(lh + l * 4);
        outv = h4;
        ushort4 u4;
        u4.x = f2bf(h4[0]); u4.y = f2bf(h4[1]); u4.z = f2bf(h4[2]); u4.w = f2bf(h4[3]);
        union { ushort4 s; unsigned long long q; } pk; pk.s = u4;
        __hip_atomic_store((unsigned long long*)(hw + hsto + (rbase + l) * 8), pk.q,
                           __ATOMIC_RELAXED, __HIP_MEMORY_SCOPE_AGENT);
      }
    }

    // ---- barrier arrival (16x16 tree); NO fence anywhere ----
    if (k < T_) {
      __syncthreads();                      // drain h stores block-wide
      if (tid == 0) {
        unsigned old = __hip_atomic_fetch_add(&gctr[grp * 1024 + k], 1u,
                                              __ATOMIC_RELAXED, __HIP_MEMORY_SCOPE_AGENT);
        if (old == 15u) {
          unsigned oldr = __hip_atomic_fetch_add(&rctr[k], 1u,
                                                 __ATOMIC_RELAXED, __HIP_MEMORY_SCOPE_AGENT);
          if (oldr == 15u) {
            #pragma unroll
            for (int gg = 0; gg < 16; ++gg)
              __hip_atomic_store(&gflag[gg * 1024 + k], 1u,
                                 __ATOMIC_RELAXED, __HIP_MEMORY_SCOPE_AGENT);
          }
        }
      }
    }

    // ---- overlap window: out stores + x[k+1]@Wx0 slice (dead-time work) ----
    if (active && l < 16) {
      const int row = rbase + l;
      if (layer) {
        *(f32x4*)(out + (size_t)row * 524288u + (size_t)(k - 1) * 1024u + bid * 4) = outv;
        if (k == T_)
          *(f32x4*)(out + HS_OFF + 65536 + row * 1024 + bid * 4) = outv;
      } else if (k == T_ - 1) {
        *(f32x4*)(out + HS_OFF + row * 1024 + bid * 4) = outv;
      }
    }
    if (k + 1 < T_) {
      const unsigned short* xt = xb + (size_t)(k + 1) * 65536u;
      f32x4 xa = {0.f, 0.f, 0.f, 0.f};
      #pragma unroll
      for (int kk = 0; kk < 16; ++kk) {
        bf16x8 ax = *(const bf16x8*)(xt + ae0 + kk * 32);
        bf16x8 b  = *(const bf16x8*)(smem + lb0 + ((kb2 + kk * 64) ^ swz));
        xa = __builtin_amdgcn_mfma_f32_16x16x32_bf16(ax, b, xa, 0, 0, 0);
      }
      if (w >= 4) {   // publish K-half-1 partial; consumed at step k+1 finalize
        float* xr = xred + (size_t)(w & 3) * 256 + (size_t)l * 4;
        #pragma unroll
        for (int v = 0; v < 4; ++v) xr[v] = xa[v];
      } else {
        xacc = xa;
      }
    }

    // ---- barrier wait (per-group flag line); syncthreads = ordering fence ----
    if (k < T_) {
      if (tid == 0) {
        unsigned spins = 0;
        while (__hip_atomic_load(&gflag[grp * 1024 + k], __ATOMIC_RELAXED, __HIP_MEMORY_SCOPE_AGENT) == 0u) {
          __builtin_amdgcn_s_sleep(1);
          if (++spins > 67108864u) break;   // safety: never wedge the GPU
        }
      }
      __syncthreads();
    }
  }

  // final cell states (rare, scattered is fine)
  if ((l & 3) == 0) {
    #pragma unroll
    for (int v = 0; v < 4; ++v)
      out[CS_OFF + layer * 65536 + (rbase + (l >> 4) * 4 + v) * 1024 + jg] = cr[v];
  }
}

extern "C" void kernel_launch(void* const* d_in, const int* in_sizes, int n_in,
                              void* d_out, int out_size, void* d_ws, size_t ws_size,
                              hipStream_t stream) {
  const float* x   = (const float*)d_in[0];
  const float* h0  = (const float*)d_in[1];
  const float* c0  = (const float*)d_in[2];
  const float* Wx0 = (const float*)d_in[3];
  const float* Wh0 = (const float*)d_in[4];
  const float* b0  = (const float*)d_in[5];
  const float* Wx1 = (const float*)d_in[6];
  const float* Wh1 = (const float*)d_in[7];
  const float* b1  = (const float*)d_in[8];
  float* out = (float*)d_out;
  char* ws = (char*)d_ws;
  if (ws_size < (size_t)WS_MIN) return;   // workspace too small -> fail loudly

  unsigned* ctr       = (unsigned*)(ws + WS_CTR);
  unsigned short* wp  = (unsigned short*)(ws + WS_W);
  float* biasP        = (float*)(ws + WS_BIAS);
  unsigned short* xbp = (unsigned short*)(ws + WS_XB);
  unsigned short* h0r = (unsigned short*)(ws + WS_H0);
  unsigned short* h1r = (unsigned short*)(ws + WS_H1);

  (void)hipMemsetAsync(ctr, 0, 139264, stream);
  hipLaunchKernelGGL(kw,    dim3(4096),  dim3(256), 0, stream, Wx0, Wh0, Wx1, Wh1, wp);
  hipLaunchKernelGGL(kx,    dim3(32768), dim3(256), 0, stream, x, xbp);
  hipLaunchKernelGGL(kmisc, dim3(544),   dim3(256), 0, stream, b0, b1, h0, biasP, h0r, h1r);

  (void)hipFuncSetAttribute((const void*)klstm, hipFuncAttributeMaxDynamicSharedMemorySize, 145408);
  const float* c0a = c0; const unsigned short* wpa = wp; const float* bpa = biasP;
  const unsigned short* xba = xbp;
  unsigned short* h0a = h0r; unsigned short* h1a = h1r;
  unsigned* ca = ctr; float* oa = out;
  void* args[] = {&c0a, &wpa, &bpa, &xba, &h0a, &h1a, &ca, &oa};
  hipError_t e = hipLaunchCooperativeKernel((const void*)klstm, dim3(NBLK), dim3(TPB),
                                            args, 145408, stream);
  if (e != hipSuccess) {
    hipLaunchKernelGGL(klstm, dim3(NBLK), dim3(TPB), 145408, stream,
                       c0a, wpa, bpa, xba, h0a, h1a, ca, oa);
  }
}